// Round 1
// baseline (186.124 us; speedup 1.0000x reference)
//
#include <hip/hip_runtime.h>
#include <math.h>

#define N_POSE   1024
#define M_TRAIN  10000
#define NJOINT   21
#define NT       4        // query rows per block
#define NCHUNK   4        // M split
#define MCHUNK   (M_TRAIN / NCHUNK)   // 2500
#define TPB      256
#define KNEIGH   5
#define CLIPV    (1.0f - 1e-7f)
#define BIGF     1e30f

__device__ __forceinline__ float acos_fast(float x) {
    // Abramowitz & Stegun 4.4.45: abs err <= ~1.8e-4 on [0,1]
    float a = fabsf(x);
    float p = fmaf(a, -0.0187293f, 0.0742610f);
    p = fmaf(a, p, -0.2121144f);
    p = fmaf(a, p, 1.5707288f);
    float r = sqrtf(1.0f - a) * p;
    return (x >= 0.0f) ? r : (3.14159265358979f - r);
}

__global__ __launch_bounds__(TPB)
void pose_dist_kernel(const float* __restrict__ pose,
                      const float* __restrict__ train,
                      float* __restrict__ ws) {
    __shared__ float4 poseS[NT][NJOINT];
    __shared__ float  red[NT][TPB * KNEIGH];

    const int bid = blockIdx.x;
    const int nb  = bid / NCHUNK;   // query-row group
    const int cb  = bid % NCHUNK;   // m-chunk
    const int n0  = nb * NT;
    const int t   = threadIdx.x;

    // cooperative load + normalize of the 4 query poses (21 quats each)
    if (t < NT * NJOINT) {
        int nl = t / NJOINT, j = t % NJOINT;
        float4 q = *(const float4*)(pose + (size_t)(n0 + nl) * NJOINT * 4 + j * 4);
        float inv = rsqrtf(q.x*q.x + q.y*q.y + q.z*q.z + q.w*q.w);
        q.x *= inv; q.y *= inv; q.z *= inv; q.w *= inv;
        poseS[nl][j] = q;
    }
    __syncthreads();

    // per-thread sorted (ascending) top-5 per local row
    float top[NT][KNEIGH];
#pragma unroll
    for (int nl = 0; nl < NT; ++nl)
#pragma unroll
        for (int k = 0; k < KNEIGH; ++k) top[nl][k] = BIGF;

    const int mbeg = cb * MCHUNK;
    for (int m = mbeg + t; m < mbeg + MCHUNK; m += TPB) {
        float acc[NT] = {0.f, 0.f, 0.f, 0.f};
        const float* tr = train + (size_t)m * NJOINT * 4;
#pragma unroll 7
        for (int j = 0; j < NJOINT; ++j) {
            float4 q = *(const float4*)(tr + j * 4);
#pragma unroll
            for (int nl = 0; nl < NT; ++nl) {
                float4 p = poseS[nl][j];
                float d = q.x*p.x + q.y*p.y + q.z*p.z + q.w*p.w;
                d = fminf(fmaxf(d, -CLIPV), CLIPV);
                acc[nl] += acos_fast(d);
            }
        }
#pragma unroll
        for (int nl = 0; nl < NT; ++nl) {
            float v = acc[nl] * 0.5f;
            float t0 = top[nl][0], t1 = top[nl][1], t2 = top[nl][2],
                  t3 = top[nl][3], t4 = top[nl][4];
            top[nl][4] = fminf(t4, fmaxf(t3, v));
            top[nl][3] = fminf(t3, fmaxf(t2, v));
            top[nl][2] = fminf(t2, fmaxf(t1, v));
            top[nl][1] = fminf(t1, fmaxf(t0, v));
            top[nl][0] = fminf(t0, v);
        }
    }

    // dump per-thread candidates
#pragma unroll
    for (int nl = 0; nl < NT; ++nl)
#pragma unroll
        for (int k = 0; k < KNEIGH; ++k)
            red[nl][t * KNEIGH + k] = top[nl][k];
    __syncthreads();

    // wave w extracts the 5 global minima of row w's 1280 candidates
    const int wave = t >> 6, lane = t & 63;
    for (int r = 0; r < KNEIGH; ++r) {
        float v = BIGF; int idx = -1;
        for (int i = lane; i < TPB * KNEIGH; i += 64) {
            float x = red[wave][i];
            if (x < v) { v = x; idx = i; }
        }
        for (int off = 32; off; off >>= 1) {
            float ov = __shfl_xor(v, off);
            int   oi = __shfl_xor(idx, off);
            if (ov < v || (ov == v && oi < idx)) { v = ov; idx = oi; }
        }
        if (lane == 0) {
            red[wave][idx] = BIGF;   // remove and record
            ws[((size_t)(n0 + wave) * NCHUNK + cb) * KNEIGH + r] = v;
        }
        __syncthreads();
    }
}

__global__ __launch_bounds__(TPB)
void pose_reduce_kernel(const float* __restrict__ ws, float* __restrict__ out) {
    int n = blockIdx.x * blockDim.x + threadIdx.x;
    if (n >= N_POSE) return;
    float t0 = BIGF, t1 = BIGF, t2 = BIGF, t3 = BIGF, t4 = BIGF;
    const float* w = ws + (size_t)n * NCHUNK * KNEIGH;
#pragma unroll
    for (int i = 0; i < NCHUNK * KNEIGH; ++i) {
        float v = w[i];
        t4 = fminf(t4, fmaxf(t3, v));
        t3 = fminf(t3, fmaxf(t2, v));
        t2 = fminf(t2, fmaxf(t1, v));
        t1 = fminf(t1, fmaxf(t0, v));
        t0 = fminf(t0, v);
    }
    out[n] = (t0 + t1 + t2 + t3 + t4) * 0.2f;
}

extern "C" void kernel_launch(void* const* d_in, const int* in_sizes, int n_in,
                              void* d_out, int out_size, void* d_ws, size_t ws_size,
                              hipStream_t stream) {
    const float* pose  = (const float*)d_in[0];
    const float* train = (const float*)d_in[1];
    float* out = (float*)d_out;
    float* ws  = (float*)d_ws;   // N_POSE * NCHUNK * KNEIGH floats = 80 KB

    dim3 grid1((N_POSE / NT) * NCHUNK);
    pose_dist_kernel<<<grid1, TPB, 0, stream>>>(pose, train, ws);

    dim3 grid2((N_POSE + TPB - 1) / TPB);
    pose_reduce_kernel<<<grid2, TPB, 0, stream>>>(ws, out);
}

// Round 2
// 134.898 us; speedup vs baseline: 1.3797x; 1.3797x over previous
//
#include <hip/hip_runtime.h>
#include <math.h>

#define N_POSE   1024
#define M_TRAIN  10000
#define NJOINT   21
#define TPB      256
#define KNEIGH   5
#define CLIPV    (1.0f - 1e-7f)
#define PI_F     3.14159265358979f
#define BIGF     1e30f

// A&S 4.4.45 poly (abs err ~1.8e-4) with raw v_sqrt_f32 (no ocml fixup code)
__device__ __forceinline__ float acos_fast(float d) {
    float a = fminf(fabsf(d), CLIPV);           // clamp folded into abs+min
    float p = fmaf(a, -0.0187293f, 0.0742610f);
    p = fmaf(a, p, -0.2121144f);
    p = fmaf(a, p, 1.5707288f);
    float r = __builtin_amdgcn_sqrtf(1.0f - a) * p;
    return (d >= 0.0f) ? r : (PI_F - r);
}

// thread = one query row (21 quats live in 84 VGPRs); block-uniform m-chunk.
// train reads are wave-uniform -> scalar-load / single-line cached, no LDS.
__global__ __launch_bounds__(TPB)
void pose_dist_kernel(const float* __restrict__ pose,
                      const float* __restrict__ train,
                      float* __restrict__ ws,
                      int chunks, int mchunk) {
    const int nb = blockIdx.x / chunks;   // query group (0..3)
    const int cb = blockIdx.x % chunks;   // m-chunk
    const int n  = nb * TPB + threadIdx.x;

    float4 q[NJOINT];
    const float4* __restrict__ pp = (const float4*)(pose + (size_t)n * NJOINT * 4);
#pragma unroll
    for (int j = 0; j < NJOINT; ++j) {
        float4 v = pp[j];
        float inv = rsqrtf(v.x*v.x + v.y*v.y + v.z*v.z + v.w*v.w);
        v.x *= inv; v.y *= inv; v.z *= inv; v.w *= inv;
        q[j] = v;
    }

    float t0 = BIGF, t1 = BIGF, t2 = BIGF, t3 = BIGF, t4 = BIGF;
    const float4* __restrict__ tr4 = (const float4*)train;
    const int mbeg = cb * mchunk;

    for (int mi = 0; mi < mchunk; ++mi) {
        const float4* __restrict__ tq = tr4 + (size_t)(mbeg + mi) * NJOINT;
        float a0 = 0.f, a1 = 0.f, a2 = 0.f;   // 3 accs: shorten dependent add chain
#pragma unroll
        for (int j = 0; j < NJOINT; ++j) {
            float4 p = q[j];
            float4 u = tq[j];                 // wave-uniform address
            float d = u.x*p.x + u.y*p.y + u.z*p.z + u.w*p.w;
            float r = acos_fast(d);
            if (j % 3 == 0) a0 += r; else if (j % 3 == 1) a1 += r; else a2 += r;
        }
        float v = (a0 + a1 + a2) * 0.5f;
        // branchless sorted insert (ascending top-5)
        t4 = fminf(t4, fmaxf(t3, v));
        t3 = fminf(t3, fmaxf(t2, v));
        t2 = fminf(t2, fmaxf(t1, v));
        t1 = fminf(t1, fmaxf(t0, v));
        t0 = fminf(t0, v);
    }

    float* w = ws + ((size_t)n * chunks + cb) * KNEIGH;
    w[0] = t0; w[1] = t1; w[2] = t2; w[3] = t3; w[4] = t4;
}

// one wave per query row: merge chunks*5 candidates -> mean of top-5
__global__ __launch_bounds__(64)
void pose_reduce_kernel(const float* __restrict__ ws, float* __restrict__ out,
                        int chunks) {
    const int n = blockIdx.x;
    const int lane = threadIdx.x;
    const int total = chunks * KNEIGH;
    const float* __restrict__ w = ws + (size_t)n * total;

    float t0 = BIGF, t1 = BIGF, t2 = BIGF, t3 = BIGF, t4 = BIGF;
    for (int i = lane; i < total; i += 64) {
        float v = w[i];
        t4 = fminf(t4, fmaxf(t3, v));
        t3 = fminf(t3, fmaxf(t2, v));
        t2 = fminf(t2, fmaxf(t1, v));
        t1 = fminf(t1, fmaxf(t0, v));
        t0 = fminf(t0, v);
    }

    float sum = 0.f;
#pragma unroll
    for (int r = 0; r < KNEIGH; ++r) {
        float v = t0; int who = lane;
        for (int off = 32; off; off >>= 1) {
            float ov = __shfl_xor(v, off);
            int   ow = __shfl_xor(who, off);
            if (ov < v || (ov == v && ow < who)) { v = ov; who = ow; }
        }
        sum += v;
        if (lane == who) { t0 = t1; t1 = t2; t2 = t3; t3 = t4; t4 = BIGF; }
    }
    if (lane == 0) out[n] = sum * (1.0f / KNEIGH);
}

extern "C" void kernel_launch(void* const* d_in, const int* in_sizes, int n_in,
                              void* d_out, int out_size, void* d_ws, size_t ws_size,
                              hipStream_t stream) {
    const float* pose  = (const float*)d_in[0];
    const float* train = (const float*)d_in[1];
    float* out = (float*)d_out;
    float* ws  = (float*)d_ws;

    // pick the largest chunk tier (all divide 10000) that fits in ws
    int chunks = 250;
    if ((size_t)N_POSE * chunks * KNEIGH * sizeof(float) > ws_size) chunks = 125;
    if ((size_t)N_POSE * chunks * KNEIGH * sizeof(float) > ws_size) chunks = 50;
    if ((size_t)N_POSE * chunks * KNEIGH * sizeof(float) > ws_size) chunks = 10;
    const int mchunk = M_TRAIN / chunks;

    dim3 grid1((N_POSE / TPB) * chunks);
    pose_dist_kernel<<<grid1, TPB, 0, stream>>>(pose, train, ws, chunks, mchunk);

    pose_reduce_kernel<<<dim3(N_POSE), dim3(64), 0, stream>>>(ws, out, chunks);
}

// Round 3
// 113.295 us; speedup vs baseline: 1.6428x; 1.1907x over previous
//
#include <hip/hip_runtime.h>
#include <math.h>

#define N_POSE   1024
#define M_TRAIN  10000
#define NJOINT   21
#define TPB      64       // one wave per block: no barriers, max scheduling freedom
#define KNEIGH   5
#define CLIPV    (1.0f - 1e-7f)
#define PI_F     3.14159265358979f
#define BIGF     1e30f

// A&S 4.4.45 poly (abs err ~1.8e-4) with raw v_sqrt_f32 (no ocml fixup code)
__device__ __forceinline__ float acos_fast(float d) {
    float a = fminf(fabsf(d), CLIPV);           // clamp folded into abs+min
    float p = fmaf(a, -0.0187293f, 0.0742610f);
    p = fmaf(a, p, -0.2121144f);
    p = fmaf(a, p, 1.5707288f);
    float r = __builtin_amdgcn_sqrtf(1.0f - a) * p;
    return (d >= 0.0f) ? r : (PI_F - r);
}

// load 7 train quats of joint-group G for train pose M into register buffer BUF
#define LOADG(BUF, M, G) do {                                                  \
    const float4* _p = tq + (size_t)(M) * NJOINT + (G) * 7;                    \
    _Pragma("unroll")                                                          \
    for (int jj = 0; jj < 7; ++jj) BUF[jj] = _p[jj];                           \
} while (0)

// accumulate acos(dot) for joint-group G (joints G*7..G*7+6) from BUF
#define COMPG(BUF, G) do {                                                     \
    _Pragma("unroll")                                                          \
    for (int jj = 0; jj < 7; ++jj) {                                           \
        float4 p = q[(G) * 7 + jj];                                            \
        float4 u = BUF[jj];                                                    \
        float d = u.x * p.x + u.y * p.y + u.z * p.z + u.w * p.w;               \
        float r = acos_fast(d);                                                \
        if (jj & 1) acc1 += r; else acc0 += r;                                 \
    }                                                                          \
} while (0)

#define INSERT(V) do {                                                         \
    float _v = (V);                                                            \
    t4 = fminf(t4, fmaxf(t3, _v));                                             \
    t3 = fminf(t3, fmaxf(t2, _v));                                             \
    t2 = fminf(t2, fmaxf(t1, _v));                                             \
    t1 = fminf(t1, fmaxf(t0, _v));                                             \
    t0 = fminf(t0, _v);                                                        \
} while (0)

// thread = one query row; 21 query quats live in 84 VGPRs (all static indices).
// Train reads are wave-uniform, double-buffered 7-quat groups (A/B) so each
// load has ~200 VALU cycles of cover before its first use.
__global__ __launch_bounds__(TPB, 2)
void pose_dist_kernel(const float* __restrict__ pose,
                      const float* __restrict__ train,
                      float* __restrict__ ws,
                      int chunks, int mchunk) {
    const int nb = blockIdx.x / chunks;   // query group (0..15)
    const int cb = blockIdx.x % chunks;   // m-chunk
    const int n  = nb * TPB + threadIdx.x;

    float4 q[NJOINT];
    const float4* __restrict__ pp = (const float4*)(pose + (size_t)n * NJOINT * 4);
#pragma unroll
    for (int j = 0; j < NJOINT; ++j) {
        float4 v = pp[j];
        float inv = rsqrtf(v.x * v.x + v.y * v.y + v.z * v.z + v.w * v.w);
        v.x *= inv; v.y *= inv; v.z *= inv; v.w *= inv;
        q[j] = v;
    }

    float t0 = BIGF, t1 = BIGF, t2 = BIGF, t3 = BIGF, t4 = BIGF;
    const float4* __restrict__ tq = (const float4*)train + (size_t)cb * mchunk * NJOINT;

    float4 A[7], B[7];
    LOADG(A, 0, 0);
    // mchunk is even for all chunk tiers (40/80/200/1000)
    for (int mi = 0; mi < mchunk; mi += 2) {
        float acc0 = 0.f, acc1 = 0.f;
        LOADG(B, mi, 1);      COMPG(A, 0);
        LOADG(A, mi, 2);      COMPG(B, 1);
        LOADG(B, mi + 1, 0);  COMPG(A, 2);
        INSERT((acc0 + acc1) * 0.5f);
        acc0 = 0.f; acc1 = 0.f;
        LOADG(A, mi + 1, 1);  COMPG(B, 0);
        LOADG(B, mi + 1, 2);  COMPG(A, 1);
        {   // prefetch first group of m+2 (clamped at chunk end to stay in bounds)
            const int m2 = (mi + 2 < mchunk) ? (mi + 2) : (mi + 1);
            LOADG(A, m2, 0);
        }
        COMPG(B, 2);
        INSERT((acc0 + acc1) * 0.5f);
    }

    float* w = ws + ((size_t)n * chunks + cb) * KNEIGH;
    w[0] = t0; w[1] = t1; w[2] = t2; w[3] = t3; w[4] = t4;
}

// one wave per query row: merge chunks*5 candidates -> mean of top-5
__global__ __launch_bounds__(64)
void pose_reduce_kernel(const float* __restrict__ ws, float* __restrict__ out,
                        int chunks) {
    const int n = blockIdx.x;
    const int lane = threadIdx.x;
    const int total = chunks * KNEIGH;
    const float* __restrict__ w = ws + (size_t)n * total;

    float t0 = BIGF, t1 = BIGF, t2 = BIGF, t3 = BIGF, t4 = BIGF;
    for (int i = lane; i < total; i += 64) {
        float v = w[i];
        t4 = fminf(t4, fmaxf(t3, v));
        t3 = fminf(t3, fmaxf(t2, v));
        t2 = fminf(t2, fmaxf(t1, v));
        t1 = fminf(t1, fmaxf(t0, v));
        t0 = fminf(t0, v);
    }

    float sum = 0.f;
#pragma unroll
    for (int r = 0; r < KNEIGH; ++r) {
        float v = t0; int who = lane;
        for (int off = 32; off; off >>= 1) {
            float ov = __shfl_xor(v, off);
            int   ow = __shfl_xor(who, off);
            if (ov < v || (ov == v && ow < who)) { v = ov; who = ow; }
        }
        sum += v;
        if (lane == who) { t0 = t1; t1 = t2; t2 = t3; t3 = t4; t4 = BIGF; }
    }
    if (lane == 0) out[n] = sum * (1.0f / KNEIGH);
}

extern "C" void kernel_launch(void* const* d_in, const int* in_sizes, int n_in,
                              void* d_out, int out_size, void* d_ws, size_t ws_size,
                              hipStream_t stream) {
    const float* pose  = (const float*)d_in[0];
    const float* train = (const float*)d_in[1];
    float* out = (float*)d_out;
    float* ws  = (float*)d_ws;

    // pick the largest chunk tier (all divide 10000, all give even mchunk)
    int chunks = 250;
    if ((size_t)N_POSE * chunks * KNEIGH * sizeof(float) > ws_size) chunks = 125;
    if ((size_t)N_POSE * chunks * KNEIGH * sizeof(float) > ws_size) chunks = 50;
    if ((size_t)N_POSE * chunks * KNEIGH * sizeof(float) > ws_size) chunks = 10;
    const int mchunk = M_TRAIN / chunks;

    dim3 grid1((N_POSE / TPB) * chunks);
    pose_dist_kernel<<<grid1, TPB, 0, stream>>>(pose, train, ws, chunks, mchunk);

    pose_reduce_kernel<<<dim3(N_POSE), dim3(64), 0, stream>>>(ws, out, chunks);
}